// Round 12
// baseline (122.623 us; speedup 1.0000x reference)
//
#include <hip/hip_runtime.h>
#include <math.h>

#define BINS 10

// Problem constants: BATCH=8388608, NUM_CLASSES=2
constexpr int   NPAIRS = 4194304;       // float4 quads (2 rows x 2 classes each)
constexpr float NTOT_F = 16777216.0f;   // BATCH * NUM_CLASSES

constexpr int G1      = 2048;
constexpr int BLK     = 256;
constexpr int NTHREAD = G1 * BLK;             // 524288
constexpr int NCHUNK  = NPAIRS / 2;           // 2097152 chunks of 2 quads (8 el)
constexpr int ITERS   = NCHUNK / NTHREAD;     // 4 exact -> 32 el/thread

constexpr int SLOTS = 19;   // 0..8 = P_1..P_9, 9 = sumL (=P_0), 10..18 = N_1..N_9

// Workspace: arr[slot*G1 + block] f32 = 19*2048*4 = 155648 B
constexpr size_t WS_ARR = 0;

typedef float v2f __attribute__((ext_vector_type(2)));

// z-domain thresholds: bin>=i <=> t=e^z >= T_i=i/(9.9999-i) <=> z >= ln(T_i).
// Compares depend only on z (not the exp result) -> issue during transcendental
// latency. Boundary shifts <=1 ulp vs t-domain (monotone), same as R10's ulps.
__constant__ const float LH[9] = {
    -2.19721347f,   // ln(1/8.9999)
    -1.38628186f,   // ln(2/7.9999)
    -0.84728357f,   // ln(3/6.9999)
    -0.40544844f,   // ln(4/5.9999)
     0.00002000f,   // ln(5/4.9999)
     0.40549011f,   // ln(6/3.9999)
     0.84733119f,   // ln(7/2.9999)
     1.38634436f,   // ln(8/1.9999)
     2.19732458f    // ln(9/0.9999)
};

// Hot-path ledger (main µs): LDS f32 atomics 92 (R4), fused+device-fence 180
// (R8), ballot/popc 44 (R7), LDS RMW 37 (R2/3), VGPR cndmask 28-30 (R5/R9),
// threshold-prefix ~25 (R10, best total 117.8). R12: z-domain compares (ILP) +
// packed (P,N) v_pk_fma (3 ops/bin/el instead of 4). Epilogue = R10 columns
// (R11's shuffle-tree epilogue regressed).
__device__ __forceinline__ void proc(float x, bool y1,
                                     v2f* __restrict__ PN, float& sumL) {
    // z = (y==1) ? -x : x ; t = e^z ; bce = ln(1+t) = ln2*log2(1+t)
    float z = y1 ? -x : x;
    float t = __builtin_amdgcn_exp2f(z * 1.4426950408889634f);
    float u = 1.0f + t;
    float l = __builtin_amdgcn_logf(u);  // log2(u); ln2 applied once at the end
    sumL += l;                           // P_0
    v2f m = {l, 1.0f};                   // (P += hitf*l, N += hitf*1) in one pk_fma
#pragma unroll
    for (int i = 0; i < BINS - 1; ++i) {
        float hitf = (z >= LH[i]) ? 1.0f : 0.0f;   // v_cmp + v_cndmask
        v2f h = {hitf, hitf};                       // op_sel broadcast, no extra op
        PN[i] = __builtin_elementwise_fma(m, h, PN[i]);   // v_pk_fma_f32
    }
}

__global__ __launch_bounds__(BLK) void ghm_main(const float4* __restrict__ x4,
                                                const int4*   __restrict__ t4,
                                                float*        __restrict__ arr) {
    const int tid  = threadIdx.x;
    const int lane = tid & 63;
    const int wave = tid >> 6;

    v2f PN[BINS - 1];
#pragma unroll
    for (int b = 0; b < BINS - 1; ++b) PN[b] = v2f{0.0f, 0.0f};
    float sumL = 0.0f;

    // chunk c covers quads {2c, 2c+1}: two dwordx4 x-loads + one dwordx4 t-load
    const int cbase = blockIdx.x * BLK + tid;
#pragma unroll
    for (int k = 0; k < ITERS; ++k) {
        int c = cbase + k * NTHREAD;
        float4 xa = x4[2 * c];
        float4 xb = x4[2 * c + 1];
        int4   tv = t4[c];
        // element (row, cls): y = (target[row] == cls)
        proc(xa.x, tv.x == 0, PN, sumL);
        proc(xa.y, tv.x == 1, PN, sumL);
        proc(xa.z, tv.y == 0, PN, sumL);
        proc(xa.w, tv.y == 1, PN, sumL);
        proc(xb.x, tv.z == 0, PN, sumL);
        proc(xb.y, tv.z == 1, PN, sumL);
        proc(xb.z, tv.w == 0, PN, sumL);
        proc(xb.w, tv.w == 1, PN, sumL);
    }

    // ---- block reduce through conflict-free LDS columns (19 slots, R10) ----
    __shared__ float cols[SLOTS * BLK];   // 19456 B
#pragma unroll
    for (int b = 0; b < BINS - 1; ++b) cols[b * BLK + tid] = PN[b].x;
    cols[9 * BLK + tid] = sumL;
#pragma unroll
    for (int b = 0; b < BINS - 1; ++b)
        cols[(10 + b) * BLK + tid] = PN[b].y;   // counts <=32 -> exact in f32
    __syncthreads();

    // wave w reduces slots {w, w+4, ...}: 4 strided reads + 6-step shuffle tree
    for (int s = wave; s < SLOTS; s += 4) {
        float v = cols[s * BLK + lane]       + cols[s * BLK + lane + 64]
                + cols[s * BLK + lane + 128] + cols[s * BLK + lane + 192];
        for (int off = 32; off > 0; off >>= 1) v += __shfl_down(v, off, 64);
        if (lane == 0) arr[s * G1 + blockIdx.x] = v;   // slot-major for final
    }
}

// Final: 10 waves; wave w reduces slots {w, w+10}. Prefix->bin via adjacent
// differences in f64; thread 0 forms beta per reference fp32 arithmetic and
// writes the mean. Deterministic.
__global__ __launch_bounds__(640) void ghm_final(const float* __restrict__ arr,
                                                 float*       __restrict__ out) {
    const int wave = threadIdx.x >> 6;   // 0..9
    const int lane = threadIdx.x & 63;
    __shared__ double Red[SLOTS];
    for (int s = wave; s < SLOTS; s += 10) {
        double v = 0.0;
#pragma unroll
        for (int k = 0; k < G1 / 64; ++k) v += (double)arr[s * G1 + k * 64 + lane];
        for (int off = 32; off > 0; off >>= 1) v += __shfl_down(v, off, 64);
        if (lane == 0) Red[s] = v;
    }
    __syncthreads();
    if (threadIdx.x == 0) {
        // prefix arrays: Pp[0]=sumL, Pp[1..9]=Red[0..8], Pp[10]=0; same for counts
        double Pp[BINS + 1], Np[BINS + 1];
        Pp[0] = Red[9];            Np[0] = (double)NTOT_F;
#pragma unroll
        for (int i = 1; i <= 9; ++i) { Pp[i] = Red[i - 1]; Np[i] = Red[9 + i]; }
        Pp[10] = 0.0; Np[10] = 0.0;

        double Sb[BINS], Cb[BINS];
#pragma unroll
        for (int b = 0; b < BINS; ++b) {
            Sb[b] = Pp[b] - Pp[b + 1];
            Cb[b] = Np[b] - Np[b + 1];
        }
        float nonempty = 0.0f;
#pragma unroll
        for (int b = 0; b < BINS; ++b) nonempty += (Cb[b] > 0.0) ? 1.0f : 0.0f;
        double tot = 0.0;
#pragma unroll
        for (int b = 0; b < BINS; ++b) {
            float gd   = fmaxf((float)Cb[b] * nonempty, 0.0001f);  // ref fp32 math
            float beta = NTOT_F / gd;
            tot += (double)beta * Sb[b];
        }
        // bce sums kept in log2; apply ln2 once, then mean
        out[0] = (float)(tot * 0.693147180559945309 / (double)NTOT_F);
    }
}

extern "C" void kernel_launch(void* const* d_in, const int* in_sizes, int n_in,
                              void* d_out, int out_size, void* d_ws, size_t ws_size,
                              hipStream_t stream) {
    const float4* x4 = (const float4*)d_in[0];   // [B,2] fp32 -> 2 rows per float4
    const int4*   t4 = (const int4*)d_in[1];     // int32 targets -> 4 rows per int4

    float* arr = (float*)((char*)d_ws + WS_ARR);
    float* out = (float*)d_out;

    ghm_main <<<G1, BLK, 0, stream>>>(x4, t4, arr);
    ghm_final<<<1, 640, 0, stream>>>(arr, out);
}

// Round 13
// 116.678 us; speedup vs baseline: 1.0510x; 1.0510x over previous
//
#include <hip/hip_runtime.h>
#include <math.h>

#define BINS 10

// Problem constants: BATCH=8388608, NUM_CLASSES=2
constexpr int   NPAIRS = 4194304;       // float4 quads (2 rows x 2 classes each)
constexpr float NTOT_F = 16777216.0f;   // BATCH * NUM_CLASSES

constexpr int G1      = 2048;
constexpr int BLK     = 256;
constexpr int NTHREAD = G1 * BLK;             // 524288
constexpr int NCHUNK  = NPAIRS / 2;           // 2097152 chunks of 2 quads (8 el)
constexpr int ITERS   = NCHUNK / NTHREAD;     // 4 exact -> 32 el/thread

constexpr int SLOTS = 19;   // 0..8 = P_1..P_9, 9 = sumL (=P_0), 10..18 = N_1..N_9

// Workspace: arr[slot*G1 + block] f32 = 19*2048*4 = 155648 B
constexpr size_t WS_ARR = 0;

// Prefix thresholds: bin>=i  <=>  g = t/(1+t) >= i/9.9999  <=>  t >= T_i,
// T_i = i/(9.9999-i) (host-computed in double, stored fp32).
__constant__ const float TH[9] = {
    0.11111234569273214f,   // 1/8.9999
    0.25000312503906297f,   // 2/7.9999
    0.42857755110787297f,   // 3/6.9999
    0.66667777796296605f,   // 4/5.9999
    1.00002000040000800f,   // 5/4.9999
    1.50003750093752340f,   // 6/3.9999
    2.33341111370379013f,   // 7/2.9999
    4.00020001000050002f,   // 8/1.9999
    9.00090009000900090f    // 9/0.9999
};

// Hot-path ledger (main-kernel µs): LDS f32 atomics 92 (R4), fused+device-fence
// 180 (R8), ballot/popc 44 (R7), LDS RMW 37 (R2/3), VGPR cndmask 28-30 (R5/R9),
// threshold-prefix ~25 (R10 -- BEST, total 117.8). R11 (shuffle-tree epilogue)
// and R12 (z-compares + pk_fma) both regressed: fewer instructions but more
// registers/latency. This is the exact R10 source.
__device__ __forceinline__ void proc(float x, bool y1,
                                     float* __restrict__ P, float& sumL,
                                     unsigned* __restrict__ N) {
    // z = (y==1) ? -x : x ; t = e^z ; bce = ln(1+t) = ln2*log2(1+t)
    float z = y1 ? -x : x;
    float t = __builtin_amdgcn_exp2f(z * 1.4426950408889634f);
    float u = 1.0f + t;
    float l = __builtin_amdgcn_logf(u);  // log2(u); ln2 applied once at the end
    sumL += l;                           // P_0
#pragma unroll
    for (int i = 0; i < BINS - 1; ++i) {
        bool hit = t >= TH[i];           // one v_cmp, shared by both accumulates
        P[i] += hit ? l : 0.0f;          // v_cndmask + v_add
        N[i] += hit ? 1u : 0u;           // v_addc
    }
}

__global__ __launch_bounds__(BLK) void ghm_main(const float4* __restrict__ x4,
                                                const int4*   __restrict__ t4,
                                                float*        __restrict__ arr) {
    const int tid  = threadIdx.x;
    const int lane = tid & 63;
    const int wave = tid >> 6;

    float P[BINS - 1];
    unsigned N[BINS - 1];
#pragma unroll
    for (int b = 0; b < BINS - 1; ++b) { P[b] = 0.0f; N[b] = 0u; }
    float sumL = 0.0f;

    // chunk c covers quads {2c, 2c+1}: two dwordx4 x-loads + one dwordx4 t-load
    const int cbase = blockIdx.x * BLK + tid;
#pragma unroll
    for (int k = 0; k < ITERS; ++k) {
        int c = cbase + k * NTHREAD;
        float4 xa = x4[2 * c];
        float4 xb = x4[2 * c + 1];
        int4   tv = t4[c];
        // element (row, cls): y = (target[row] == cls)
        proc(xa.x, tv.x == 0, P, sumL, N);
        proc(xa.y, tv.x == 1, P, sumL, N);
        proc(xa.z, tv.y == 0, P, sumL, N);
        proc(xa.w, tv.y == 1, P, sumL, N);
        proc(xb.x, tv.z == 0, P, sumL, N);
        proc(xb.y, tv.z == 1, P, sumL, N);
        proc(xb.z, tv.w == 0, P, sumL, N);
        proc(xb.w, tv.w == 1, P, sumL, N);
    }

    // ---- block reduce through conflict-free LDS columns (19 slots) ----
    __shared__ float cols[SLOTS * BLK];   // 19456 B
#pragma unroll
    for (int b = 0; b < BINS - 1; ++b) cols[b * BLK + tid] = P[b];
    cols[9 * BLK + tid] = sumL;
#pragma unroll
    for (int b = 0; b < BINS - 1; ++b)
        cols[(10 + b) * BLK + tid] = (float)N[b];   // <=32 -> exact in f32
    __syncthreads();

    // wave w reduces slots {w, w+4, ...}: 4 strided reads + 6-step shuffle tree
    for (int s = wave; s < SLOTS; s += 4) {
        float v = cols[s * BLK + lane]       + cols[s * BLK + lane + 64]
                + cols[s * BLK + lane + 128] + cols[s * BLK + lane + 192];
        for (int off = 32; off > 0; off >>= 1) v += __shfl_down(v, off, 64);
        if (lane == 0) arr[s * G1 + blockIdx.x] = v;   // slot-major for final
    }
}

// Final: 10 waves; wave w reduces slots {w, w+10}. Prefix->bin via adjacent
// differences in f64; thread 0 forms beta per reference fp32 arithmetic and
// writes the mean. Deterministic.
__global__ __launch_bounds__(640) void ghm_final(const float* __restrict__ arr,
                                                 float*       __restrict__ out) {
    const int wave = threadIdx.x >> 6;   // 0..9
    const int lane = threadIdx.x & 63;
    __shared__ double Red[SLOTS];
    for (int s = wave; s < SLOTS; s += 10) {
        double v = 0.0;
#pragma unroll
        for (int k = 0; k < G1 / 64; ++k) v += (double)arr[s * G1 + k * 64 + lane];
        for (int off = 32; off > 0; off >>= 1) v += __shfl_down(v, off, 64);
        if (lane == 0) Red[s] = v;
    }
    __syncthreads();
    if (threadIdx.x == 0) {
        // prefix arrays: Pp[0]=sumL, Pp[1..9]=Red[0..8], Pp[10]=0; same for counts
        double Pp[BINS + 1], Np[BINS + 1];
        Pp[0] = Red[9];            Np[0] = (double)NTOT_F;
#pragma unroll
        for (int i = 1; i <= 9; ++i) { Pp[i] = Red[i - 1]; Np[i] = Red[9 + i]; }
        Pp[10] = 0.0; Np[10] = 0.0;

        double Sb[BINS], Cb[BINS];
#pragma unroll
        for (int b = 0; b < BINS; ++b) {
            Sb[b] = Pp[b] - Pp[b + 1];
            Cb[b] = Np[b] - Np[b + 1];
        }
        float nonempty = 0.0f;
#pragma unroll
        for (int b = 0; b < BINS; ++b) nonempty += (Cb[b] > 0.0) ? 1.0f : 0.0f;
        double tot = 0.0;
#pragma unroll
        for (int b = 0; b < BINS; ++b) {
            float gd   = fmaxf((float)Cb[b] * nonempty, 0.0001f);  // ref fp32 math
            float beta = NTOT_F / gd;
            tot += (double)beta * Sb[b];
        }
        // bce sums kept in log2; apply ln2 once, then mean
        out[0] = (float)(tot * 0.693147180559945309 / (double)NTOT_F);
    }
}

extern "C" void kernel_launch(void* const* d_in, const int* in_sizes, int n_in,
                              void* d_out, int out_size, void* d_ws, size_t ws_size,
                              hipStream_t stream) {
    const float4* x4 = (const float4*)d_in[0];   // [B,2] fp32 -> 2 rows per float4
    const int4*   t4 = (const int4*)d_in[1];     // int32 targets -> 4 rows per int4

    float* arr = (float*)((char*)d_ws + WS_ARR);
    float* out = (float*)d_out;

    ghm_main <<<G1, BLK, 0, stream>>>(x4, t4, arr);
    ghm_final<<<1, 640, 0, stream>>>(arr, out);
}